// Round 1
// baseline (244.410 us; speedup 1.0000x reference)
//
#include <hip/hip_runtime.h>
#include <hip/hip_bf16.h>
#include <stdint.h>

#define BATCH 16384
#define DM    256
#define KC    4352   // 2048 + 1024 + 512 + 768
#define NCLS  26

typedef __bf16 bf16;
typedef __attribute__((ext_vector_type(8))) __bf16 bf16x8;
typedef __attribute__((ext_vector_type(4))) float f32x4;

// ---- workspace layout (bytes) ----
#define WCAT_OFF  0u          // 256*4352*2 = 2228224
#define P_OFF     2228224u    // 256*256*4  = 262144
#define CC_OFF    2490368u    // 1024
#define GT_OFF    2491392u    // 256*256*2  = 131072
#define G_OFF     2622464u    // 1024
#define BSUM_OFF  2623488u    // 1024
#define CS_OFF    2624512u    // 1024
#define CQ_OFF    2625536u    // 1024
#define SD_OFF    2626560u    // 1024
#define TD_OFF    2627584u    // 1024
#define FBAR_OFF  2628608u    // 16384*256*2 = 8388608
#define H_OFF     11017216u   // 16384*256*4 = 16777216  -> total ~27.8 MB

__device__ __forceinline__ bf16x8 cvt8(float4 a, float4 b) {
  bf16x8 r;
  r[0] = (bf16)a.x; r[1] = (bf16)a.y; r[2] = (bf16)a.z; r[3] = (bf16)a.w;
  r[4] = (bf16)b.x; r[5] = (bf16)b.y; r[6] = (bf16)b.z; r[7] = (bf16)b.w;
  return r;
}

__device__ __forceinline__ void gld_lds16(const void* g, void* l) {
  __builtin_amdgcn_global_load_lds(
      (const __attribute__((address_space(1))) void*)g,
      (__attribute__((address_space(3))) void*)l, 16, 0, 0);
}

// ---- Pre1: build Wcat (bf16, 256 x 4352 k-contiguous), bsum, zero stat accumulators ----
__global__ __launch_bounds__(256) void k_pre1(
    const float* __restrict__ w0, const float* __restrict__ w1,
    const float* __restrict__ w2, const float* __restrict__ w3,
    const float* __restrict__ b0, const float* __restrict__ b1,
    const float* __restrict__ b2, const float* __restrict__ b3,
    bf16* __restrict__ Wcat, float* __restrict__ bsum,
    float* __restrict__ cs, float* __restrict__ cq) {
  int idx = blockIdx.x * 256 + threadIdx.x;
  const int tot = DM * KC / 8;  // 139264
  if (idx < tot) {
    int e = idx * 8;
    int d = e / KC;
    int k = e - d * KC;
    const float* src; int o;
    if (k < 2048)      { src = w0 + d * 2048; o = k; }
    else if (k < 3072) { src = w1 + d * 1024; o = k - 2048; }
    else if (k < 3584) { src = w2 + d * 512;  o = k - 3072; }
    else               { src = w3 + d * 768;  o = k - 3584; }
    float4 a = *(const float4*)(src + o);
    float4 b = *(const float4*)(src + o + 4);
    *(bf16x8*)(Wcat + (size_t)d * KC + k) = cvt8(a, b);
  }
  if (blockIdx.x == gridDim.x - 1) {
    int d = threadIdx.x;
    bsum[d] = b0[d] + b1[d] + b2[d] + b3[d];
    cs[d] = 0.f; cq[d] = 0.f;
  }
}

// ---- Pre2: P[i][o] = sum_j w_v[j][i]*out_w[o][j]; cc[o] = sum_j b_v[j]*out_w[o][j] + out_b[o] ----
__global__ __launch_bounds__(256) void k_pre2(
    const float* __restrict__ in_proj_w, const float* __restrict__ in_proj_b,
    const float* __restrict__ out_w, const float* __restrict__ out_b,
    float* __restrict__ P, float* __restrict__ cc) {
  int i = blockIdx.x;     // 0..255 -> P row; 256 -> cc
  int o = threadIdx.x;
  if (i < 256) {
    float s = 0.f;
    for (int j = 0; j < 256; ++j)
      s += in_proj_w[(512 + j) * 256 + i] * out_w[o * 256 + j];
    P[i * 256 + o] = s;
  } else {
    float s = 0.f;
    for (int j = 0; j < 256; ++j)
      s += in_proj_b[512 + j] * out_w[o * 256 + j];
    cc[o] = s + out_b[o];
  }
}

// ---- Pre3: GT[j][i] = sum_o (P[i][o] + (i==o)) * fc1_w[j][o]  (bf16, k=i contiguous); g[j] ----
__global__ __launch_bounds__(256) void k_pre3(
    const float* __restrict__ P, const float* __restrict__ cc,
    const float* __restrict__ fc1_w, const float* __restrict__ fc1_b,
    bf16* __restrict__ GT, float* __restrict__ g) {
  int j = blockIdx.x;
  int i = threadIdx.x;
  float s = 0.f;
  for (int o = 0; o < 256; ++o)
    s += (P[i * 256 + o] + (i == o ? 1.f : 0.f)) * fc1_w[j * 256 + o];
  GT[j * 256 + i] = (bf16)s;
  if (i == 0) {
    float t = 0.f;
    for (int o = 0; o < 256; ++o) t += cc[o] * fc1_w[j * 256 + o];
    g[j] = t + fc1_b[j];
  }
}

// ---- K1: fbar = 0.25*(Xcat @ Wcat^T + bsum), bf16 MFMA, BM=128 BN=64 BK=32 ----
__global__ __launch_bounds__(256) void k_gemm1(
    const float* __restrict__ x0, const float* __restrict__ x1,
    const float* __restrict__ x2, const float* __restrict__ x3,
    const bf16* __restrict__ Wcat, const float* __restrict__ bsum,
    bf16* __restrict__ fbar) {
  __shared__ bf16 lA[128 * 32];
  __shared__ bf16 lB[64 * 32];
  int bid = blockIdx.x;
  int tile = (bid & 7) * 64 + (bid >> 3);   // XCD swizzle (512 % 8 == 0, bijective)
  int mt = tile >> 2, nt = tile & 3;
  int tid = threadIdx.x;
  int lane = tid & 63, wid = tid >> 6;
  int wr = wid >> 1, wc = wid & 1;          // 2x2 waves, wave tile 64x32
  int fr = lane & 15, fq = lane >> 4;
  f32x4 acc[4][2] = {};
  int ar = tid >> 2;                        // A-stage row within 64-row half
  int ak = (tid & 3) * 8;                   // A-stage k offset (floats)
  int brow = nt * 64 + (tid >> 2);
  int bk = (tid & 3) * 8;
  const bf16* bbase = Wcat + (size_t)brow * KC + bk;

  for (int kt = 0; kt < KC / 32; ++kt) {
    int k0 = kt * 32;
    const float* xs; int L, ko;
    if (k0 < 2048)      { xs = x0; L = 2048; ko = k0; }
    else if (k0 < 3072) { xs = x1; L = 1024; ko = k0 - 2048; }
    else if (k0 < 3584) { xs = x2; L = 512;  ko = k0 - 3072; }
    else                { xs = x3; L = 768;  ko = k0 - 3584; }
    const float4* ap0 = (const float4*)(xs + (size_t)(mt * 128 + ar) * L + ko + ak);
    const float4* ap1 = (const float4*)(xs + (size_t)(mt * 128 + 64 + ar) * L + ko + ak);
    float4 a0 = ap0[0], a1 = ap0[1];
    float4 c0 = ap1[0], c1 = ap1[1];
    __syncthreads();                         // previous tile fully consumed
    gld_lds16(bbase + k0, lB + tid * 8);     // B: 64x32 bf16 via async direct-to-LDS
    *(bf16x8*)(lA + tid * 8)        = cvt8(a0, a1);   // conflict-free linear writes
    *(bf16x8*)(lA + 2048 + tid * 8) = cvt8(c0, c1);
    __syncthreads();
#pragma unroll
    for (int m = 0; m < 4; ++m) {
      bf16x8 av = *(const bf16x8*)(lA + (wr * 64 + m * 16 + fr) * 32 + fq * 8);
#pragma unroll
      for (int n = 0; n < 2; ++n) {
        bf16x8 bv = *(const bf16x8*)(lB + (wc * 32 + n * 16 + fr) * 32 + fq * 8);
        acc[m][n] = __builtin_amdgcn_mfma_f32_16x16x32_bf16(av, bv, acc[m][n], 0, 0, 0);
      }
    }
  }
#pragma unroll
  for (int n = 0; n < 2; ++n) {
    int col = nt * 64 + wc * 32 + n * 16 + fr;
    float bs = bsum[col];
#pragma unroll
    for (int m = 0; m < 4; ++m) {
      int row = mt * 128 + wr * 64 + m * 16 + fq * 4;
#pragma unroll
      for (int r = 0; r < 4; ++r)
        fbar[(size_t)(row + r) * DM + col] = (bf16)(0.25f * (acc[m][n][r] + bs));
    }
  }
}

// ---- K2: h = fbar @ GT^T + g  (+ column sum/sumsq for batchnorm) ----
__global__ __launch_bounds__(256) void k_gemm2(
    const bf16* __restrict__ fbar, const bf16* __restrict__ GT,
    const float* __restrict__ g, float* __restrict__ h,
    float* __restrict__ cs, float* __restrict__ cq) {
  __shared__ bf16 lA[128 * 32];
  __shared__ bf16 lB[64 * 32];
  int bid = blockIdx.x;
  int tile = (bid & 7) * 64 + (bid >> 3);
  int mt = tile >> 2, nt = tile & 3;
  int tid = threadIdx.x;
  int lane = tid & 63, wid = tid >> 6;
  int wr = wid >> 1, wc = wid & 1;
  int fr = lane & 15, fq = lane >> 4;
  f32x4 acc[4][2] = {};
  int ar = tid >> 2;
  int ak = (tid & 3) * 8;

  for (int kt = 0; kt < 8; ++kt) {
    int k0 = kt * 32;
    __syncthreads();
    gld_lds16(fbar + (size_t)(mt * 128 + ar) * DM + k0 + ak,      lA + tid * 8);
    gld_lds16(fbar + (size_t)(mt * 128 + 64 + ar) * DM + k0 + ak, lA + 2048 + tid * 8);
    gld_lds16(GT + (size_t)(nt * 64 + ar) * DM + k0 + ak,         lB + tid * 8);
    __syncthreads();
#pragma unroll
    for (int m = 0; m < 4; ++m) {
      bf16x8 av = *(const bf16x8*)(lA + (wr * 64 + m * 16 + fr) * 32 + fq * 8);
#pragma unroll
      for (int n = 0; n < 2; ++n) {
        bf16x8 bv = *(const bf16x8*)(lB + (wc * 32 + n * 16 + fr) * 32 + fq * 8);
        acc[m][n] = __builtin_amdgcn_mfma_f32_16x16x32_bf16(av, bv, acc[m][n], 0, 0, 0);
      }
    }
  }
#pragma unroll
  for (int n = 0; n < 2; ++n) {
    int col = nt * 64 + wc * 32 + n * 16 + fr;
    float gv = g[col];
    float s = 0.f, q = 0.f;
#pragma unroll
    for (int m = 0; m < 4; ++m) {
      int row = mt * 128 + wr * 64 + m * 16 + fq * 4;
#pragma unroll
      for (int r = 0; r < 4; ++r) {
        float v = acc[m][n][r] + gv;
        h[(size_t)(row + r) * DM + col] = v;
        s += v; q += v * v;
      }
    }
    s += __shfl_xor(s, 16); s += __shfl_xor(s, 32);
    q += __shfl_xor(q, 16); q += __shfl_xor(q, 32);
    if (fq == 0) { atomicAdd(&cs[col], s); atomicAdd(&cq[col], q); }
  }
}

// ---- stats finalize: per-channel scale/shift ----
__global__ void k_stats(const float* __restrict__ cs, const float* __restrict__ cq,
                        const float* __restrict__ bn_g, const float* __restrict__ bn_b,
                        float* __restrict__ sd, float* __restrict__ td) {
  int d = threadIdx.x;
  float mu = cs[d] * (1.f / 16384.f);
  float var = cq[d] * (1.f / 16384.f) - mu * mu;
  float s = bn_g[d] * rsqrtf(var + 1e-5f);
  sd[d] = s;
  td[d] = bn_b[d] - mu * s;
}

// ---- K3: out = relu(h*s + t) @ fc2^T + fc2_b, one wave per row ----
__global__ __launch_bounds__(256) void k_fc2(
    const float* __restrict__ h, const float* __restrict__ sd, const float* __restrict__ td,
    const float* __restrict__ fc2_w, const float* __restrict__ fc2_b,
    float* __restrict__ out) {
  int wid = threadIdx.x >> 6, lane = threadIdx.x & 63;
  int row = blockIdx.x * 4 + wid;
  float4 hv = *(const float4*)(h + (size_t)row * 256 + lane * 4);
  float4 s  = *(const float4*)(sd + lane * 4);
  float4 t  = *(const float4*)(td + lane * 4);
  float y0 = fmaxf(hv.x * s.x + t.x, 0.f);
  float y1 = fmaxf(hv.y * s.y + t.y, 0.f);
  float y2 = fmaxf(hv.z * s.z + t.z, 0.f);
  float y3 = fmaxf(hv.w * s.w + t.w, 0.f);
  for (int c = 0; c < NCLS; ++c) {
    float4 w = *(const float4*)(fc2_w + c * 256 + lane * 4);
    float p = y0 * w.x + y1 * w.y + y2 * w.z + y3 * w.w;
#pragma unroll
    for (int off = 32; off; off >>= 1) p += __shfl_xor(p, off);
    if (lane == 0) out[row * NCLS + c] = p + fc2_b[c];
  }
}

extern "C" void kernel_launch(void* const* d_in, const int* in_sizes, int n_in,
                              void* d_out, int out_size, void* d_ws, size_t ws_size,
                              hipStream_t stream) {
  (void)in_sizes; (void)n_in; (void)out_size; (void)ws_size;
  const float* x0 = (const float*)d_in[0];
  const float* x1 = (const float*)d_in[1];
  const float* x2 = (const float*)d_in[2];
  const float* x3 = (const float*)d_in[3];
  const float* w0 = (const float*)d_in[4];
  const float* b0 = (const float*)d_in[5];
  const float* w1 = (const float*)d_in[6];
  const float* b1 = (const float*)d_in[7];
  const float* w2 = (const float*)d_in[8];
  const float* b2 = (const float*)d_in[9];
  const float* w3 = (const float*)d_in[10];
  const float* b3 = (const float*)d_in[11];
  const float* in_proj_w = (const float*)d_in[12];
  const float* in_proj_b = (const float*)d_in[13];
  const float* out_w = (const float*)d_in[14];
  const float* out_b = (const float*)d_in[15];
  // gate (16..19) is mathematically dead: feats_cross == feats_self
  const float* fc1_w = (const float*)d_in[20];
  const float* fc1_b = (const float*)d_in[21];
  const float* bn_g = (const float*)d_in[22];
  const float* bn_b = (const float*)d_in[23];
  const float* fc2_w = (const float*)d_in[24];
  const float* fc2_b = (const float*)d_in[25];

  char* ws = (char*)d_ws;
  bf16* Wcat = (bf16*)(ws + WCAT_OFF);
  float* P   = (float*)(ws + P_OFF);
  float* cc  = (float*)(ws + CC_OFF);
  bf16* GT   = (bf16*)(ws + GT_OFF);
  float* g   = (float*)(ws + G_OFF);
  float* bsum= (float*)(ws + BSUM_OFF);
  float* cs  = (float*)(ws + CS_OFF);
  float* cq  = (float*)(ws + CQ_OFF);
  float* sd  = (float*)(ws + SD_OFF);
  float* td  = (float*)(ws + TD_OFF);
  bf16* fbar = (bf16*)(ws + FBAR_OFF);
  float* h   = (float*)(ws + H_OFF);
  float* out = (float*)d_out;

  k_pre1<<<dim3(545), dim3(256), 0, stream>>>(w0, w1, w2, w3, b0, b1, b2, b3, Wcat, bsum, cs, cq);
  k_pre2<<<dim3(257), dim3(256), 0, stream>>>(in_proj_w, in_proj_b, out_w, out_b, P, cc);
  k_pre3<<<dim3(256), dim3(256), 0, stream>>>(P, cc, fc1_w, fc1_b, GT, g);
  k_gemm1<<<dim3(512), dim3(256), 0, stream>>>(x0, x1, x2, x3, Wcat, bsum, fbar);
  k_gemm2<<<dim3(512), dim3(256), 0, stream>>>(fbar, GT, g, h, cs, cq);
  k_stats<<<dim3(1), dim3(256), 0, stream>>>(cs, cq, bn_g, bn_b, sd, td);
  k_fc2<<<dim3(4096), dim3(256), 0, stream>>>(h, sd, td, fc2_w, fc2_b, out);
}

// Round 2
// 237.189 us; speedup vs baseline: 1.0304x; 1.0304x over previous
//
#include <hip/hip_runtime.h>
#include <hip/hip_bf16.h>
#include <stdint.h>

#define DM    256
#define KC    4352   // 2048 + 1024 + 512 + 768
#define NCLS  26

typedef __bf16 bf16;
typedef __attribute__((ext_vector_type(8))) __bf16 bf16x8;
typedef __attribute__((ext_vector_type(4))) __bf16 bf16x4;
typedef __attribute__((ext_vector_type(4))) float f32x4;

// ---- workspace layout (bytes) ----
#define WCAT_OFF  0u          // 256*4352*2 = 2228224  (pre-swizzled)
#define P_OFF     2228224u    // 256*256*4  = 262144
#define CC_OFF    2490368u    // 1024
#define GT_OFF    2491392u    // 256*256*2  = 131072   (pre-swizzled)
#define G_OFF     2622464u    // 1024
#define BSUM_OFF  2623488u    // 1024
#define CS_OFF    2624512u    // 1024
#define CQ_OFF    2625536u    // 1024
#define SD_OFF    2626560u    // 1024
#define TD_OFF    2627584u    // 1024
#define FBAR_OFF  2628608u    // 16384*256*2 = 8388608 (pre-swizzled)
#define H_OFF     11017216u   // 16384*256*2 = 8388608 (bf16 now)

__device__ __forceinline__ bf16x8 cvt8(float4 a, float4 b) {
  bf16x8 r;
  r[0] = (bf16)a.x; r[1] = (bf16)a.y; r[2] = (bf16)a.z; r[3] = (bf16)a.w;
  r[4] = (bf16)b.x; r[5] = (bf16)b.y; r[6] = (bf16)b.z; r[7] = (bf16)b.w;
  return r;
}

__device__ __forceinline__ void gld_lds16(const void* g, void* l) {
  __builtin_amdgcn_global_load_lds(
      (const __attribute__((address_space(1))) void*)g,
      (__attribute__((address_space(3))) void*)l, 16, 0, 0);
}

__device__ __forceinline__ const float* pick(const float* x0, const float* x1,
                                             const float* x2, const float* x3,
                                             int k0, int& L, int& ko) {
  if (k0 < 2048)      { L = 2048; ko = k0;        return x0; }
  else if (k0 < 3072) { L = 1024; ko = k0 - 2048; return x1; }
  else if (k0 < 3584) { L = 512;  ko = k0 - 3072; return x2; }
  else                { L = 768;  ko = k0 - 3584; return x3; }
}

// ---- Pre12: Wcat (bf16, pre-swizzled chunks) + bsum + zero stats; and P/cc ----
__global__ __launch_bounds__(256) void k_pre12(
    const float* __restrict__ w0, const float* __restrict__ w1,
    const float* __restrict__ w2, const float* __restrict__ w3,
    const float* __restrict__ b0, const float* __restrict__ b1,
    const float* __restrict__ b2, const float* __restrict__ b3,
    const float* __restrict__ in_proj_w, const float* __restrict__ in_proj_b,
    const float* __restrict__ out_w, const float* __restrict__ out_b,
    bf16* __restrict__ Wcat, float* __restrict__ bsum,
    float* __restrict__ cs, float* __restrict__ cq,
    float* __restrict__ P, float* __restrict__ cc) {
  int bid = blockIdx.x;
  if (bid < 544) {                       // 544*256*8 == 256*4352 exactly
    int idx = bid * 256 + threadIdx.x;
    int e = idx * 8;
    int d = e / KC;
    int k = e - d * KC;
    const float* src; int o;
    if (k < 2048)      { src = w0 + d * 2048; o = k; }
    else if (k < 3072) { src = w1 + d * 1024; o = k - 2048; }
    else if (k < 3584) { src = w2 + d * 512;  o = k - 3072; }
    else               { src = w3 + d * 768;  o = k - 3584; }
    float4 a = *(const float4*)(src + o);
    float4 b = *(const float4*)(src + o + 4);
    // swizzle 8-elem chunk within its 64-elem k-tile: chunk ^= (row&7)
    int ks = (k & ~63) | ((((k >> 3) & 7) ^ (d & 7)) << 3);
    *(bf16x8*)(Wcat + (size_t)d * KC + ks) = cvt8(a, b);
  } else if (bid == 544) {
    int d = threadIdx.x;
    bsum[d] = b0[d] + b1[d] + b2[d] + b3[d];
    cs[d] = 0.f; cq[d] = 0.f;
  } else {
    int i = bid - 545;                   // 0..256
    int o = threadIdx.x;
    if (i < 256) {
      float s = 0.f;
      for (int j = 0; j < 256; ++j)
        s += in_proj_w[(512 + j) * 256 + i] * out_w[o * 256 + j];
      P[i * 256 + o] = s;
    } else {
      float s = 0.f;
      for (int j = 0; j < 256; ++j)
        s += in_proj_b[512 + j] * out_w[o * 256 + j];
      cc[o] = s + out_b[o];
    }
  }
}

// ---- Pre3: GT[j][i] = sum_o (P[i][o]+(i==o))*fc1_w[j][o], pre-swizzled; g[j] ----
__global__ __launch_bounds__(256) void k_pre3(
    const float* __restrict__ P, const float* __restrict__ cc,
    const float* __restrict__ fc1_w, const float* __restrict__ fc1_b,
    bf16* __restrict__ GT, float* __restrict__ g) {
  int j = blockIdx.x;
  int i = threadIdx.x;
  float s = 0.f;
  for (int o = 0; o < 256; ++o)
    s += (P[i * 256 + o] + (i == o ? 1.f : 0.f)) * fc1_w[j * 256 + o];
  int is = (i & ~63) | ((((i >> 3) & 7) ^ (j & 7)) << 3) | (i & 7);
  GT[j * 256 + is] = (bf16)s;
  if (i == 0) {
    float t = 0.f;
    for (int o = 0; o < 256; ++o) t += cc[o] * fc1_w[j * 256 + o];
    g[j] = t + fc1_b[j];
  }
}

// ---- K1: fbar = 0.25*(Xcat @ Wcat^T + bsum). BM=64 BN=64 BK=64, 2-phase dbuf ----
__global__ __launch_bounds__(256, 4) void k_gemm1(
    const float* __restrict__ x0, const float* __restrict__ x1,
    const float* __restrict__ x2, const float* __restrict__ x3,
    const bf16* __restrict__ Wcat, const float* __restrict__ bsum,
    bf16* __restrict__ fbar) {
  __shared__ __align__(16) bf16 lds[2][8192];   // [buf][A 0..4095 | B 4096..8191]
  int bid = blockIdx.x;
  int tile = (bid & 7) * 128 + (bid >> 3);      // 1024 % 8 == 0 -> bijective
  int mt = tile >> 2, nt = tile & 3;
  int tid = threadIdx.x;
  int lane = tid & 63, wid = tid >> 6;
  int wr = wid >> 1, wc = wid & 1;              // 2x2 waves, wave tile 32x32
  int fr = lane & 15, fq = lane >> 4;
  f32x4 acc[2][2] = {};

  int sr = tid >> 2;                            // A stage row
  int sc = (tid & 3) * 2;                       // A chunk base
  int wa0 = sr * 64 + ((sc ^ (sr & 7)) << 3);
  int wa1 = sr * 64 + (((sc + 1) ^ (sr & 7)) << 3);
  const size_t brow0 = (size_t)(nt * 64 + (tid >> 3)) * KC + (tid & 7) * 8;
  const size_t brow1 = (size_t)(nt * 64 + 32 + (tid >> 3)) * KC + (tid & 7) * 8;

  float4 a0, a1, a2, a3;
  {  // prologue: stage k-tile 0 into buf 0
    gld_lds16(Wcat + brow0, &lds[0][4096 + tid * 8]);
    gld_lds16(Wcat + brow1, &lds[0][4096 + 2048 + tid * 8]);
    int L, ko; const float* xs = pick(x0, x1, x2, x3, 0, L, ko);
    const float4* ap = (const float4*)(xs + (size_t)(mt * 64 + sr) * L + ko) + (tid & 3) * 4;
    a0 = ap[0]; a1 = ap[1]; a2 = ap[2]; a3 = ap[3];
    *(bf16x8*)&lds[0][wa0] = cvt8(a0, a1);
    *(bf16x8*)&lds[0][wa1] = cvt8(a2, a3);
    __syncthreads();
  }

  for (int kt = 0; kt < 68; ++kt) {
    int cur = kt & 1;
    if (kt < 67) {                               // issue next-tile loads early
      int k0 = (kt + 1) * 64;
      gld_lds16(Wcat + brow0 + k0, &lds[cur ^ 1][4096 + tid * 8]);
      gld_lds16(Wcat + brow1 + k0, &lds[cur ^ 1][4096 + 2048 + tid * 8]);
      int L, ko; const float* xs = pick(x0, x1, x2, x3, k0, L, ko);
      const float4* ap = (const float4*)(xs + (size_t)(mt * 64 + sr) * L + ko) + (tid & 3) * 4;
      a0 = ap[0]; a1 = ap[1]; a2 = ap[2]; a3 = ap[3];
    }
    const bf16* A  = &lds[cur][0];
    const bf16* Bb = &lds[cur][4096];
    bf16x8 av[2][2], bv[2][2];
#pragma unroll
    for (int m = 0; m < 2; ++m) {
      int row = wr * 32 + m * 16 + fr;
#pragma unroll
      for (int kk = 0; kk < 2; ++kk)
        av[m][kk] = *(const bf16x8*)(A + row * 64 + ((((kk << 2) | fq) ^ (row & 7)) << 3));
    }
#pragma unroll
    for (int n = 0; n < 2; ++n) {
      int row = wc * 32 + n * 16 + fr;
#pragma unroll
      for (int kk = 0; kk < 2; ++kk)
        bv[n][kk] = *(const bf16x8*)(Bb + row * 64 + ((((kk << 2) | fq) ^ (row & 7)) << 3));
    }
#pragma unroll
    for (int kk = 0; kk < 2; ++kk)
#pragma unroll
      for (int m = 0; m < 2; ++m)
#pragma unroll
        for (int n = 0; n < 2; ++n)
          acc[m][n] = __builtin_amdgcn_mfma_f32_16x16x32_bf16(av[m][kk], bv[n][kk], acc[m][n], 0, 0, 0);
    __builtin_amdgcn_sched_barrier(0);           // keep next-tile writes after MFMA
    if (kt < 67) {
      *(bf16x8*)&lds[cur ^ 1][wa0] = cvt8(a0, a1);
      *(bf16x8*)&lds[cur ^ 1][wa1] = cvt8(a2, a3);
    }
    __syncthreads();                             // single barrier per K-step
  }

#pragma unroll
  for (int n = 0; n < 2; ++n) {
    int col = nt * 64 + wc * 32 + n * 16 + fr;
    float bs = bsum[col];
#pragma unroll
    for (int m = 0; m < 2; ++m) {
      int row0 = mt * 64 + wr * 32 + m * 16 + fq * 4;
#pragma unroll
      for (int r = 0; r < 4; ++r) {
        int row = row0 + r;
        int csw = (col & ~63) | ((((col >> 3) & 7) ^ (row & 7)) << 3) | (col & 7);
        fbar[(size_t)row * DM + csw] = (bf16)(0.25f * (acc[m][n][r] + bs));
      }
    }
  }
}

// ---- K2: h = fbar @ GT^T + g (bf16 out) + column stats. K=256, 4 dbuf steps ----
__global__ __launch_bounds__(256, 4) void k_gemm2(
    const bf16* __restrict__ fbar, const bf16* __restrict__ GT,
    const float* __restrict__ g, bf16* __restrict__ h,
    float* __restrict__ cs, float* __restrict__ cq) {
  __shared__ __align__(16) bf16 lds[2][8192];
  int bid = blockIdx.x;
  int tile = (bid & 7) * 128 + (bid >> 3);
  int mt = tile >> 2, nt = tile & 3;
  int tid = threadIdx.x;
  int lane = tid & 63, wid = tid >> 6;
  int wr = wid >> 1, wc = wid & 1;
  int fr = lane & 15, fq = lane >> 4;
  f32x4 acc[2][2] = {};

  const size_t arow0 = (size_t)(mt * 64 + (tid >> 3)) * DM + (tid & 7) * 8;
  const size_t arow1 = (size_t)(mt * 64 + 32 + (tid >> 3)) * DM + (tid & 7) * 8;
  const size_t grow0 = (size_t)(nt * 64 + (tid >> 3)) * DM + (tid & 7) * 8;
  const size_t grow1 = (size_t)(nt * 64 + 32 + (tid >> 3)) * DM + (tid & 7) * 8;

  gld_lds16(fbar + arow0, &lds[0][tid * 8]);
  gld_lds16(fbar + arow1, &lds[0][2048 + tid * 8]);
  gld_lds16(GT + grow0, &lds[0][4096 + tid * 8]);
  gld_lds16(GT + grow1, &lds[0][4096 + 2048 + tid * 8]);
  __syncthreads();

  for (int kt = 0; kt < 4; ++kt) {
    int cur = kt & 1;
    if (kt < 3) {
      int k0 = (kt + 1) * 64;
      gld_lds16(fbar + arow0 + k0, &lds[cur ^ 1][tid * 8]);
      gld_lds16(fbar + arow1 + k0, &lds[cur ^ 1][2048 + tid * 8]);
      gld_lds16(GT + grow0 + k0, &lds[cur ^ 1][4096 + tid * 8]);
      gld_lds16(GT + grow1 + k0, &lds[cur ^ 1][4096 + 2048 + tid * 8]);
    }
    const bf16* A  = &lds[cur][0];
    const bf16* Bb = &lds[cur][4096];
    bf16x8 av[2][2], bv[2][2];
#pragma unroll
    for (int m = 0; m < 2; ++m) {
      int row = wr * 32 + m * 16 + fr;
#pragma unroll
      for (int kk = 0; kk < 2; ++kk)
        av[m][kk] = *(const bf16x8*)(A + row * 64 + ((((kk << 2) | fq) ^ (row & 7)) << 3));
    }
#pragma unroll
    for (int n = 0; n < 2; ++n) {
      int row = wc * 32 + n * 16 + fr;
#pragma unroll
      for (int kk = 0; kk < 2; ++kk)
        bv[n][kk] = *(const bf16x8*)(Bb + row * 64 + ((((kk << 2) | fq) ^ (row & 7)) << 3));
    }
#pragma unroll
    for (int kk = 0; kk < 2; ++kk)
#pragma unroll
      for (int m = 0; m < 2; ++m)
#pragma unroll
        for (int n = 0; n < 2; ++n)
          acc[m][n] = __builtin_amdgcn_mfma_f32_16x16x32_bf16(av[m][kk], bv[n][kk], acc[m][n], 0, 0, 0);
    __syncthreads();
  }

#pragma unroll
  for (int n = 0; n < 2; ++n) {
    int col = nt * 64 + wc * 32 + n * 16 + fr;
    float gv = g[col];
    float s = 0.f, q = 0.f;
#pragma unroll
    for (int m = 0; m < 2; ++m) {
      int row0 = mt * 64 + wr * 32 + m * 16 + fq * 4;
#pragma unroll
      for (int r = 0; r < 4; ++r) {
        float v = acc[m][n][r] + gv;
        h[(size_t)(row0 + r) * DM + col] = (bf16)v;
        s += v; q += v * v;
      }
    }
    s += __shfl_xor(s, 16); s += __shfl_xor(s, 32);
    q += __shfl_xor(q, 16); q += __shfl_xor(q, 32);
    if (fq == 0) { atomicAdd(&cs[col], s); atomicAdd(&cq[col], q); }
  }
}

// ---- stats finalize ----
__global__ void k_stats(const float* __restrict__ cs, const float* __restrict__ cq,
                        const float* __restrict__ bn_g, const float* __restrict__ bn_b,
                        float* __restrict__ sd, float* __restrict__ td) {
  int d = threadIdx.x;
  float mu = cs[d] * (1.f / 16384.f);
  float var = cq[d] * (1.f / 16384.f) - mu * mu;
  float s = bn_g[d] * rsqrtf(var + 1e-5f);
  sd[d] = s;
  td[d] = bn_b[d] - mu * s;
}

// ---- K3: out = relu(h*s + t) @ fc2^T + fc2_b ----
__global__ __launch_bounds__(256) void k_fc2(
    const bf16* __restrict__ h, const float* __restrict__ sd, const float* __restrict__ td,
    const float* __restrict__ fc2_w, const float* __restrict__ fc2_b,
    float* __restrict__ out) {
  int wid = threadIdx.x >> 6, lane = threadIdx.x & 63;
  int row = blockIdx.x * 4 + wid;
  bf16x4 hv = *(const bf16x4*)(h + (size_t)row * 256 + lane * 4);
  float4 s = *(const float4*)(sd + lane * 4);
  float4 t = *(const float4*)(td + lane * 4);
  float y0 = fmaxf((float)hv[0] * s.x + t.x, 0.f);
  float y1 = fmaxf((float)hv[1] * s.y + t.y, 0.f);
  float y2 = fmaxf((float)hv[2] * s.z + t.z, 0.f);
  float y3 = fmaxf((float)hv[3] * s.w + t.w, 0.f);
  for (int c = 0; c < NCLS; ++c) {
    float4 w = *(const float4*)(fc2_w + c * 256 + lane * 4);
    float p = y0 * w.x + y1 * w.y + y2 * w.z + y3 * w.w;
#pragma unroll
    for (int off = 32; off; off >>= 1) p += __shfl_xor(p, off);
    if (lane == 0) out[row * NCLS + c] = p + fc2_b[c];
  }
}

extern "C" void kernel_launch(void* const* d_in, const int* in_sizes, int n_in,
                              void* d_out, int out_size, void* d_ws, size_t ws_size,
                              hipStream_t stream) {
  (void)in_sizes; (void)n_in; (void)out_size; (void)ws_size;
  const float* x0 = (const float*)d_in[0];
  const float* x1 = (const float*)d_in[1];
  const float* x2 = (const float*)d_in[2];
  const float* x3 = (const float*)d_in[3];
  const float* w0 = (const float*)d_in[4];
  const float* b0 = (const float*)d_in[5];
  const float* w1 = (const float*)d_in[6];
  const float* b1 = (const float*)d_in[7];
  const float* w2 = (const float*)d_in[8];
  const float* b2 = (const float*)d_in[9];
  const float* w3 = (const float*)d_in[10];
  const float* b3 = (const float*)d_in[11];
  const float* in_proj_w = (const float*)d_in[12];
  const float* in_proj_b = (const float*)d_in[13];
  const float* out_w = (const float*)d_in[14];
  const float* out_b = (const float*)d_in[15];
  // gate (16..19) is mathematically dead: feats_cross == feats_self
  const float* fc1_w = (const float*)d_in[20];
  const float* fc1_b = (const float*)d_in[21];
  const float* bn_g = (const float*)d_in[22];
  const float* bn_b = (const float*)d_in[23];
  const float* fc2_w = (const float*)d_in[24];
  const float* fc2_b = (const float*)d_in[25];

  char* ws = (char*)d_ws;
  bf16* Wcat = (bf16*)(ws + WCAT_OFF);
  float* P   = (float*)(ws + P_OFF);
  float* cc  = (float*)(ws + CC_OFF);
  bf16* GT   = (bf16*)(ws + GT_OFF);
  float* g   = (float*)(ws + G_OFF);
  float* bsum= (float*)(ws + BSUM_OFF);
  float* cs  = (float*)(ws + CS_OFF);
  float* cq  = (float*)(ws + CQ_OFF);
  float* sd  = (float*)(ws + SD_OFF);
  float* td  = (float*)(ws + TD_OFF);
  bf16* fbar = (bf16*)(ws + FBAR_OFF);
  bf16* h    = (bf16*)(ws + H_OFF);
  float* out = (float*)d_out;

  k_pre12<<<dim3(802), dim3(256), 0, stream>>>(w0, w1, w2, w3, b0, b1, b2, b3,
                                               in_proj_w, in_proj_b, out_w, out_b,
                                               Wcat, bsum, cs, cq, P, cc);
  k_pre3<<<dim3(256), dim3(256), 0, stream>>>(P, cc, fc1_w, fc1_b, GT, g);
  k_gemm1<<<dim3(1024), dim3(256), 0, stream>>>(x0, x1, x2, x3, Wcat, bsum, fbar);
  k_gemm2<<<dim3(1024), dim3(256), 0, stream>>>(fbar, GT, g, h, cs, cq);
  k_stats<<<dim3(1), dim3(256), 0, stream>>>(cs, cq, bn_g, bn_b, sd, td);
  k_fc2<<<dim3(4096), dim3(256), 0, stream>>>(h, sd, td, fc2_w, fc2_b, out);
}

// Round 3
// 184.241 us; speedup vs baseline: 1.3266x; 1.2874x over previous
//
#include <hip/hip_runtime.h>
#include <hip/hip_bf16.h>
#include <stdint.h>

#define DM    256
#define KC    4352   // 2048 + 1024 + 512 + 768
#define NCLS  26

typedef __bf16 bf16;
typedef __attribute__((ext_vector_type(8))) __bf16 bf16x8;
typedef __attribute__((ext_vector_type(4))) __bf16 bf16x4;
typedef __attribute__((ext_vector_type(4))) float f32x4;

// ---- workspace layout (bytes) ----
#define WCAT_OFF  0u          // 256*4352*2 = 2228224  (pre-swizzled)
#define P_OFF     2228224u    // 256*256*4  = 262144
#define CC_OFF    2490368u    // 1024
#define GT_OFF    2491392u    // 256*256*2  = 131072   (pre-swizzled)
#define G_OFF     2622464u    // 1024
#define BSUM_OFF  2623488u    // 1024
#define CS_OFF    2624512u    // 1024
#define CQ_OFF    2625536u    // 1024
#define SD_OFF    2626560u    // 1024
#define TD_OFF    2627584u    // 1024
#define FBAR_OFF  2628608u    // 16384*256*2 = 8388608 (pre-swizzled)
#define H_OFF     11017216u   // 16384*256*2 = 8388608 (bf16)

__device__ __forceinline__ bf16x8 cvt8(float4 a, float4 b) {
  bf16x8 r;
  r[0] = (bf16)a.x; r[1] = (bf16)a.y; r[2] = (bf16)a.z; r[3] = (bf16)a.w;
  r[4] = (bf16)b.x; r[5] = (bf16)b.y; r[6] = (bf16)b.z; r[7] = (bf16)b.w;
  return r;
}

__device__ __forceinline__ void gld_lds16(const void* g, void* l) {
  __builtin_amdgcn_global_load_lds(
      (const __attribute__((address_space(1))) void*)g,
      (__attribute__((address_space(3))) void*)l, 16, 0, 0);
}

__device__ __forceinline__ const float* pick(const float* x0, const float* x1,
                                             const float* x2, const float* x3,
                                             int k0, int& L, int& ko) {
  if (k0 < 2048)      { L = 2048; ko = k0;        return x0; }
  else if (k0 < 3072) { L = 1024; ko = k0 - 2048; return x1; }
  else if (k0 < 3584) { L = 512;  ko = k0 - 3072; return x2; }
  else                { L = 768;  ko = k0 - 3584; return x3; }
}

// ---- Pre12: Wcat (bf16, pre-swizzled chunks) + bsum + zero stats; and P/cc ----
__global__ __launch_bounds__(256) void k_pre12(
    const float* __restrict__ w0, const float* __restrict__ w1,
    const float* __restrict__ w2, const float* __restrict__ w3,
    const float* __restrict__ b0, const float* __restrict__ b1,
    const float* __restrict__ b2, const float* __restrict__ b3,
    const float* __restrict__ in_proj_w, const float* __restrict__ in_proj_b,
    const float* __restrict__ out_w, const float* __restrict__ out_b,
    bf16* __restrict__ Wcat, float* __restrict__ bsum,
    float* __restrict__ cs, float* __restrict__ cq,
    float* __restrict__ P, float* __restrict__ cc) {
  int bid = blockIdx.x;
  if (bid < 544) {                       // 544*256*8 == 256*4352 exactly
    int idx = bid * 256 + threadIdx.x;
    int e = idx * 8;
    int d = e / KC;
    int k = e - d * KC;
    const float* src; int o;
    if (k < 2048)      { src = w0 + d * 2048; o = k; }
    else if (k < 3072) { src = w1 + d * 1024; o = k - 2048; }
    else if (k < 3584) { src = w2 + d * 512;  o = k - 3072; }
    else               { src = w3 + d * 768;  o = k - 3584; }
    float4 a = *(const float4*)(src + o);
    float4 b = *(const float4*)(src + o + 4);
    // swizzle 8-elem chunk within its 64-elem k-tile: chunk ^= (row&7)
    int ks = (k & ~63) | ((((k >> 3) & 7) ^ (d & 7)) << 3);
    *(bf16x8*)(Wcat + (size_t)d * KC + ks) = cvt8(a, b);
  } else if (bid == 544) {
    int d = threadIdx.x;
    bsum[d] = b0[d] + b1[d] + b2[d] + b3[d];
    cs[d] = 0.f; cq[d] = 0.f;
  } else {
    int i = bid - 545;                   // 0..256
    int o = threadIdx.x;
    if (i < 256) {
      float s = 0.f;
      for (int j = 0; j < 256; ++j)
        s += in_proj_w[(512 + j) * 256 + i] * out_w[o * 256 + j];
      P[i * 256 + o] = s;
    } else {
      float s = 0.f;
      for (int j = 0; j < 256; ++j)
        s += in_proj_b[512 + j] * out_w[o * 256 + j];
      cc[o] = s + out_b[o];
    }
  }
}

// ---- Pre3: GT[j][i] = sum_o (P[i][o]+(i==o))*fc1_w[j][o], pre-swizzled; g[j] ----
__global__ __launch_bounds__(256) void k_pre3(
    const float* __restrict__ P, const float* __restrict__ cc,
    const float* __restrict__ fc1_w, const float* __restrict__ fc1_b,
    bf16* __restrict__ GT, float* __restrict__ g) {
  int j = blockIdx.x;
  int i = threadIdx.x;
  float s = 0.f;
  for (int o = 0; o < 256; ++o)
    s += (P[i * 256 + o] + (i == o ? 1.f : 0.f)) * fc1_w[j * 256 + o];
  int is = (i & ~63) | ((((i >> 3) & 7) ^ (j & 7)) << 3) | (i & 7);
  GT[j * 256 + is] = (bf16)s;
  if (i == 0) {
    float t = 0.f;
    for (int o = 0; o < 256; ++o) t += cc[o] * fc1_w[j * 256 + o];
    g[j] = t + fc1_b[j];
  }
}

// ---- K1: fbar = 0.25*(Xcat @ Wcat^T + bsum). BM=64 BN=256 BK=64, A read ONCE ----
__global__ __launch_bounds__(512, 2) void k_gemm1(
    const float* __restrict__ x0, const float* __restrict__ x1,
    const float* __restrict__ x2, const float* __restrict__ x3,
    const bf16* __restrict__ Wcat, const float* __restrict__ bsum,
    bf16* __restrict__ fbar) {
  // per buffer: A 64x64 bf16 (4096 el) | B 256x64 bf16 (16384 el) = 40 KB; x2 = 80 KB
  __shared__ __align__(16) bf16 lds[2][20480];
  int mt = blockIdx.x;                          // 256 blocks, 1 per CU
  int tid = threadIdx.x;
  int lane = tid & 63, wid = tid >> 6;
  int wr = wid >> 2, wc = wid & 3;              // 2x4 waves, wave tile 32x64
  int fr = lane & 15, fq = lane >> 4;
  f32x4 acc[2][4] = {};

  int arow = tid >> 3;                          // 0..63 (A row; also B base row)
  int achk = tid & 7;                           // 8-float chunk / 8-bf16 chunk
  int wa = arow * 64 + ((achk ^ (arow & 7)) << 3);   // swizzled A LDS elem
  const size_t bbase = (size_t)arow * KC + achk * 8; // B rows arow + {0,64,128,192}

  float4 a0, a1;
  { // prologue: stage k-tile 0 into buf 0
#pragma unroll
    for (int j = 0; j < 4; ++j)
      gld_lds16(Wcat + bbase + (size_t)j * 64 * KC, &lds[0][4096 + tid * 8 + j * 4096]);
    int L, ko; const float* xs = pick(x0, x1, x2, x3, 0, L, ko);
    const float4* ap = (const float4*)(xs + (size_t)(mt * 64 + arow) * L + ko) + achk * 2;
    a0 = ap[0]; a1 = ap[1];
    *(bf16x8*)&lds[0][wa] = cvt8(a0, a1);
    __syncthreads();
  }

  for (int kt = 0; kt < 68; ++kt) {
    int cur = kt & 1;
    if (kt < 67) {                               // issue next-tile loads early
      int k0 = (kt + 1) * 64;
#pragma unroll
      for (int j = 0; j < 4; ++j)
        gld_lds16(Wcat + bbase + k0 + (size_t)j * 64 * KC,
                  &lds[cur ^ 1][4096 + tid * 8 + j * 4096]);
      int L, ko; const float* xs = pick(x0, x1, x2, x3, k0, L, ko);
      const float4* ap = (const float4*)(xs + (size_t)(mt * 64 + arow) * L + ko) + achk * 2;
      a0 = ap[0]; a1 = ap[1];
    }
    const bf16* A  = &lds[cur][0];
    const bf16* Bb = &lds[cur][4096];
    bf16x8 av[2][2], bv[4][2];
#pragma unroll
    for (int m = 0; m < 2; ++m) {
      int row = wr * 32 + m * 16 + fr;
#pragma unroll
      for (int kk = 0; kk < 2; ++kk)
        av[m][kk] = *(const bf16x8*)(A + row * 64 + ((((kk << 2) | fq) ^ (row & 7)) << 3));
    }
#pragma unroll
    for (int n = 0; n < 4; ++n) {
      int row = wc * 64 + n * 16 + fr;
#pragma unroll
      for (int kk = 0; kk < 2; ++kk)
        bv[n][kk] = *(const bf16x8*)(Bb + row * 64 + ((((kk << 2) | fq) ^ (row & 7)) << 3));
    }
#pragma unroll
    for (int kk = 0; kk < 2; ++kk)
#pragma unroll
      for (int m = 0; m < 2; ++m)
#pragma unroll
        for (int n = 0; n < 4; ++n)
          acc[m][n] = __builtin_amdgcn_mfma_f32_16x16x32_bf16(av[m][kk], bv[n][kk], acc[m][n], 0, 0, 0);
    __builtin_amdgcn_sched_barrier(0);           // keep next-tile A writes after MFMA
    if (kt < 67)
      *(bf16x8*)&lds[cur ^ 1][wa] = cvt8(a0, a1);
    __syncthreads();                             // single barrier per K-step
  }

#pragma unroll
  for (int n = 0; n < 4; ++n) {
    int col = wc * 64 + n * 16 + fr;
    float bs = bsum[col];
#pragma unroll
    for (int m = 0; m < 2; ++m) {
      int row0 = mt * 64 + wr * 32 + m * 16 + fq * 4;
#pragma unroll
      for (int r = 0; r < 4; ++r) {
        int row = row0 + r;
        int csw = (col & ~63) | ((((col >> 3) & 7) ^ (row & 7)) << 3) | (col & 7);
        fbar[(size_t)row * DM + csw] = (bf16)(0.25f * (acc[m][n][r] + bs));
      }
    }
  }
}

// ---- K2: h = fbar @ GT^T + g (bf16 out) + column stats. K=256, 4 dbuf steps ----
__global__ __launch_bounds__(256, 4) void k_gemm2(
    const bf16* __restrict__ fbar, const bf16* __restrict__ GT,
    const float* __restrict__ g, bf16* __restrict__ h,
    float* __restrict__ cs, float* __restrict__ cq) {
  __shared__ __align__(16) bf16 lds[2][8192];
  int bid = blockIdx.x;
  int tile = (bid & 7) * 128 + (bid >> 3);
  int mt = tile >> 2, nt = tile & 3;
  int tid = threadIdx.x;
  int lane = tid & 63, wid = tid >> 6;
  int wr = wid >> 1, wc = wid & 1;
  int fr = lane & 15, fq = lane >> 4;
  f32x4 acc[2][2] = {};

  const size_t arow0 = (size_t)(mt * 64 + (tid >> 3)) * DM + (tid & 7) * 8;
  const size_t arow1 = (size_t)(mt * 64 + 32 + (tid >> 3)) * DM + (tid & 7) * 8;
  const size_t grow0 = (size_t)(nt * 64 + (tid >> 3)) * DM + (tid & 7) * 8;
  const size_t grow1 = (size_t)(nt * 64 + 32 + (tid >> 3)) * DM + (tid & 7) * 8;

  gld_lds16(fbar + arow0, &lds[0][tid * 8]);
  gld_lds16(fbar + arow1, &lds[0][2048 + tid * 8]);
  gld_lds16(GT + grow0, &lds[0][4096 + tid * 8]);
  gld_lds16(GT + grow1, &lds[0][4096 + 2048 + tid * 8]);
  __syncthreads();

  for (int kt = 0; kt < 4; ++kt) {
    int cur = kt & 1;
    if (kt < 3) {
      int k0 = (kt + 1) * 64;
      gld_lds16(fbar + arow0 + k0, &lds[cur ^ 1][tid * 8]);
      gld_lds16(fbar + arow1 + k0, &lds[cur ^ 1][2048 + tid * 8]);
      gld_lds16(GT + grow0 + k0, &lds[cur ^ 1][4096 + tid * 8]);
      gld_lds16(GT + grow1 + k0, &lds[cur ^ 1][4096 + 2048 + tid * 8]);
    }
    const bf16* A  = &lds[cur][0];
    const bf16* Bb = &lds[cur][4096];
    bf16x8 av[2][2], bv[2][2];
#pragma unroll
    for (int m = 0; m < 2; ++m) {
      int row = wr * 32 + m * 16 + fr;
#pragma unroll
      for (int kk = 0; kk < 2; ++kk)
        av[m][kk] = *(const bf16x8*)(A + row * 64 + ((((kk << 2) | fq) ^ (row & 7)) << 3));
    }
#pragma unroll
    for (int n = 0; n < 2; ++n) {
      int row = wc * 32 + n * 16 + fr;
#pragma unroll
      for (int kk = 0; kk < 2; ++kk)
        bv[n][kk] = *(const bf16x8*)(Bb + row * 64 + ((((kk << 2) | fq) ^ (row & 7)) << 3));
    }
#pragma unroll
    for (int kk = 0; kk < 2; ++kk)
#pragma unroll
      for (int m = 0; m < 2; ++m)
#pragma unroll
        for (int n = 0; n < 2; ++n)
          acc[m][n] = __builtin_amdgcn_mfma_f32_16x16x32_bf16(av[m][kk], bv[n][kk], acc[m][n], 0, 0, 0);
    __syncthreads();
  }

#pragma unroll
  for (int n = 0; n < 2; ++n) {
    int col = nt * 64 + wc * 32 + n * 16 + fr;
    float gv = g[col];
    float s = 0.f, q = 0.f;
#pragma unroll
    for (int m = 0; m < 2; ++m) {
      int row0 = mt * 64 + wr * 32 + m * 16 + fq * 4;
#pragma unroll
      for (int r = 0; r < 4; ++r) {
        float v = acc[m][n][r] + gv;
        h[(size_t)(row0 + r) * DM + col] = (bf16)v;
        s += v; q += v * v;
      }
    }
    s += __shfl_xor(s, 16); s += __shfl_xor(s, 32);
    q += __shfl_xor(q, 16); q += __shfl_xor(q, 32);
    if (fq == 0) { atomicAdd(&cs[col], s); atomicAdd(&cq[col], q); }
  }
}

// ---- stats finalize ----
__global__ void k_stats(const float* __restrict__ cs, const float* __restrict__ cq,
                        const float* __restrict__ bn_g, const float* __restrict__ bn_b,
                        float* __restrict__ sd, float* __restrict__ td) {
  int d = threadIdx.x;
  float mu = cs[d] * (1.f / 16384.f);
  float var = cq[d] * (1.f / 16384.f) - mu * mu;
  float s = bn_g[d] * rsqrtf(var + 1e-5f);
  sd[d] = s;
  td[d] = bn_b[d] - mu * s;
}

// ---- K3: out = relu(h*s + t) @ fc2^T + fc2_b ----
__global__ __launch_bounds__(256) void k_fc2(
    const bf16* __restrict__ h, const float* __restrict__ sd, const float* __restrict__ td,
    const float* __restrict__ fc2_w, const float* __restrict__ fc2_b,
    float* __restrict__ out) {
  int wid = threadIdx.x >> 6, lane = threadIdx.x & 63;
  int row = blockIdx.x * 4 + wid;
  bf16x4 hv = *(const bf16x4*)(h + (size_t)row * 256 + lane * 4);
  float4 s = *(const float4*)(sd + lane * 4);
  float4 t = *(const float4*)(td + lane * 4);
  float y0 = fmaxf((float)hv[0] * s.x + t.x, 0.f);
  float y1 = fmaxf((float)hv[1] * s.y + t.y, 0.f);
  float y2 = fmaxf((float)hv[2] * s.z + t.z, 0.f);
  float y3 = fmaxf((float)hv[3] * s.w + t.w, 0.f);
  for (int c = 0; c < NCLS; ++c) {
    float4 w = *(const float4*)(fc2_w + c * 256 + lane * 4);
    float p = y0 * w.x + y1 * w.y + y2 * w.z + y3 * w.w;
#pragma unroll
    for (int off = 32; off; off >>= 1) p += __shfl_xor(p, off);
    if (lane == 0) out[row * NCLS + c] = p + fc2_b[c];
  }
}

extern "C" void kernel_launch(void* const* d_in, const int* in_sizes, int n_in,
                              void* d_out, int out_size, void* d_ws, size_t ws_size,
                              hipStream_t stream) {
  (void)in_sizes; (void)n_in; (void)out_size; (void)ws_size;
  const float* x0 = (const float*)d_in[0];
  const float* x1 = (const float*)d_in[1];
  const float* x2 = (const float*)d_in[2];
  const float* x3 = (const float*)d_in[3];
  const float* w0 = (const float*)d_in[4];
  const float* b0 = (const float*)d_in[5];
  const float* w1 = (const float*)d_in[6];
  const float* b1 = (const float*)d_in[7];
  const float* w2 = (const float*)d_in[8];
  const float* b2 = (const float*)d_in[9];
  const float* w3 = (const float*)d_in[10];
  const float* b3 = (const float*)d_in[11];
  const float* in_proj_w = (const float*)d_in[12];
  const float* in_proj_b = (const float*)d_in[13];
  const float* out_w = (const float*)d_in[14];
  const float* out_b = (const float*)d_in[15];
  // gate (16..19) is mathematically dead: feats_cross == feats_self
  const float* fc1_w = (const float*)d_in[20];
  const float* fc1_b = (const float*)d_in[21];
  const float* bn_g = (const float*)d_in[22];
  const float* bn_b = (const float*)d_in[23];
  const float* fc2_w = (const float*)d_in[24];
  const float* fc2_b = (const float*)d_in[25];

  char* ws = (char*)d_ws;
  bf16* Wcat = (bf16*)(ws + WCAT_OFF);
  float* P   = (float*)(ws + P_OFF);
  float* cc  = (float*)(ws + CC_OFF);
  bf16* GT   = (bf16*)(ws + GT_OFF);
  float* g   = (float*)(ws + G_OFF);
  float* bsum= (float*)(ws + BSUM_OFF);
  float* cs  = (float*)(ws + CS_OFF);
  float* cq  = (float*)(ws + CQ_OFF);
  float* sd  = (float*)(ws + SD_OFF);
  float* td  = (float*)(ws + TD_OFF);
  bf16* fbar = (bf16*)(ws + FBAR_OFF);
  bf16* h    = (bf16*)(ws + H_OFF);
  float* out = (float*)d_out;

  k_pre12<<<dim3(802), dim3(256), 0, stream>>>(w0, w1, w2, w3, b0, b1, b2, b3,
                                               in_proj_w, in_proj_b, out_w, out_b,
                                               Wcat, bsum, cs, cq, P, cc);
  k_pre3<<<dim3(256), dim3(256), 0, stream>>>(P, cc, fc1_w, fc1_b, GT, g);
  k_gemm1<<<dim3(256), dim3(512), 0, stream>>>(x0, x1, x2, x3, Wcat, bsum, fbar);
  k_gemm2<<<dim3(1024), dim3(256), 0, stream>>>(fbar, GT, g, h, cs, cq);
  k_stats<<<dim3(1), dim3(256), 0, stream>>>(cs, cq, bn_g, bn_b, sd, td);
  k_fc2<<<dim3(4096), dim3(256), 0, stream>>>(h, sd, td, fc2_w, fc2_b, out);
}